// Round 16
// baseline (48.010 us; speedup 1.0000x reference)
//
#include <hip/hip_runtime.h>

// Problem constants (fixed by the reference setup)
#define Bc   2
#define Cc   256
#define Hc   80
#define Wc   160
#define Gc   4
#define Sc   9
#define GCc  64              // channels per group
#define HWc  (Hc * Wc)
#define H2c  (Hc / 2)        // 40 row-pair tiles
#define WTc  (Wc / 32)       // 5 col tiles of 32
#define NW   4               // waves per block
#define CPW  16              // channels per wave

// fp16 vertical-pair tile: dword slot(t,x) = t*80 + dx + (t&1)*16, value =
// fp16x2(v(minY+t,x), v(minY+t+1,x)).
// R16: PARITY ROTATION. At stride 64 the 32 row-pair partner lanes (l,l+32)
// have identical dx but t differing by 1 -> same bank, different address =
// guaranteed 2-lane collision every access (R14/R15 falsified the t-smear
// model: stride 64 vs 68 conflicts identical ~8e6). Rotating odd-t rows by
// +16 banks separates the parity classes; within a class dx ~ col + noise
// keeps near-identity spread -> ~2 lanes/bank total, which is free (m136).
// No read2 wrap: max slot 62+1+16 = 79 < 80. Write quad-bank still 8
// lanes/quad (conflict-free); b128 16B alignment preserved.
// Keep R12/R15's proven config: __launch_bounds__(256,2) (>=3 spills the
// rv prefetch sets to scratch - R13/R14), distance-3 prefetch, no hard lgkm
// fence (per-wave DS ops are in-order; CFENCE pins compiler order - R6).
#define PROWS   20
#define TSTRIDE 80
#define TDW     (PROWS * TSTRIDE)    // 1600 dwords = 6400 B per buffer

typedef float f4 __attribute__((ext_vector_type(4)));
typedef _Float16 h2 __attribute__((ext_vector_type(2)));
typedef unsigned u4 __attribute__((ext_vector_type(4)));

static __device__ __forceinline__ unsigned pk(float a, float b) {
    return __builtin_bit_cast(unsigned, __builtin_amdgcn_cvt_pkrtz(a, b));
}
static __device__ __forceinline__ float dot2(unsigned w, unsigned v, float c) {
#if __has_builtin(__builtin_amdgcn_fdot2)
    return __builtin_amdgcn_fdot2(__builtin_bit_cast(h2, w),
                                  __builtin_bit_cast(h2, v), c, false);
#else
    h2 hw = __builtin_bit_cast(h2, w), hv = __builtin_bit_cast(h2, v);
    return c + (float)hw[0] * (float)hv[0] + (float)hw[1] * (float)hv[1];
#endif
}

// Compiler-only memory fence (zero instructions).
#define CFENCE() asm volatile("" ::: "memory")

// One pipeline iteration, prefetch distance 3 (R12-proven). RV/LV statically
// named (rule #20); BUF compile-time 0/1. wrow[j] = precomputed write slot
// (includes parity rotation).
#define ITER3(cI, RV, LV, BUF)                                              \
  do {                                                                      \
    CFENCE();                                                               \
    _Pragma("unroll")                                                       \
    for (int j = 0; j < 5; ++j) {                                           \
      unsigned* q = twBase + (BUF) * TDW + wrow[j];                         \
      u4 val = { pk(RV[j][0], RV[j + 1][0]), pk(RV[j][1], RV[j + 1][1]),    \
                 pk(RV[j][2], RV[j + 1][2]), pk(RV[j][3], RV[j + 1][3]) };  \
      *(u4*)q = val;   /* ds_write_b128, conflict-free by construction */   \
    }                                                                       \
    CFENCE();                                                               \
    if ((cI) + 3 < CPW) {                                                   \
      const float* Rn = Rb + (size_t)((cI) + 3) * HWc;                      \
      _Pragma("unroll")                                                     \
      for (int k = 0; k < 6; ++k) RV[k] = *(const f4*)(Rn + rowEl[k]);      \
    }                                                                       \
    {                                                                       \
      const unsigned* twr = twBase + (BUF) * TDW;                           \
      _Pragma("unroll")                                                     \
      for (int s = 0; s < Sc; ++s) {                                        \
        const unsigned d0 = twr[idx[s]];                                    \
        const unsigned d1 = twr[idx[s] + 1];                                \
        float sd = dot2(wA[s], d0, 0.0f);                                   \
        sd = dot2(wB[s], d1, sd);                                           \
        acc[s] = fmaf(LV, sd, acc[s]);                                      \
      }                                                                     \
    }                                                                       \
    if ((cI) + 3 < CPW) LV = Lb[(size_t)((cI) + 3) * HWc];                  \
  } while (0)

__global__ __launch_bounds__(256, 2)
void aoc_corr_kernel(const float* __restrict__ left,
                     const float* __restrict__ right,
                     const float* __restrict__ flow,
                     const float* __restrict__ extra,
                     float* __restrict__ out)
{
    __shared__ unsigned tile[NW][2][TDW];   // 51200 B

    // XCD chunk swizzle (R11-proven: FETCH 122->30 MB): 1600 = 8 XCDs x 200,
    // and 200 = one (b,g)'s tiles; each XCD keeps one (b,g)'s 3.3 MB
    // right-slice resident in its 4 MB L2. Bijective. Perf heuristic only.
    const int p = blockIdx.x;
    int bid = 200 * (p & 7) + (p >> 3);

    int wt = bid % WTc; bid /= WTc;
    int h2i = bid % H2c; bid /= H2c;
    int g  = bid % Gc;  bid /= Gc;
    int b  = bid;

    const int tid  = threadIdx.x;
    const int wid  = tid >> 6;
    const int lane = tid & 63;
    const int r    = lane >> 5;
    const int col  = lane & 31;
    const int h    = h2i * 2 + r;
    const int w    = wt * 32 + col;
    const int pix  = h * Wc + w;

    const float* flowb = flow + (size_t)b * 2 * HWc;
    const float bx = (float)w + flowb[pix];
    const float by = (float)h + flowb[HWc + pix];

    int   xb9[Sc], y09[Sc], y19[Sc];
    float w00[Sc], w01[Sc], w10[Sc], w11[Sc];
    int minX = 1 << 30, maxX = -(1 << 30), minY = 1 << 30, maxY = -(1 << 30);

    const float* exb = extra + (size_t)b * (2 * Sc) * HWc + pix;
#pragma unroll
    for (int s = 0; s < Sc; ++s) {
        const float ex = exb[(size_t)(2 * s) * HWc];
        const float ey = exb[(size_t)(2 * s + 1) * HWc];
        const float x = bx + (float)(s - 4) + ex;   // window: x offset s-4, y 0
        const float y = by + ey;

        const float x0f = floorf(x);
        const float y0f = floorf(y);
        const float fx = x - x0f;
        const float fy = y - y0f;
        const int x0 = (int)x0f;
        const int y0 = (int)y0f;
        const int y1 = y0 + 1;

        const int xb = min(max(x0, 0), Wc - 2);
        const float cA = (x0 == xb) ? (1.0f - fx) : ((x0 == -1)     ? fx          : 0.0f);
        const float cB = (x0 == xb) ? fx          : ((x0 == Wc - 1) ? (1.0f - fx) : 0.0f);
        const float r0 = (y0 >= 0 && y0 < Hc) ? (1.0f - fy) : 0.0f;
        const float r1 = (y1 >= 0 && y1 < Hc) ? fy          : 0.0f;
        const int yc0 = min(max(y0, 0), Hc - 1);
        const int yc1 = min(max(y1, 0), Hc - 1);

        w00[s] = cA * r0;  w01[s] = cB * r0;
        w10[s] = cA * r1;  w11[s] = cB * r1;
        xb9[s] = xb;  y09[s] = yc0;  y19[s] = yc1;

        minX = min(minX, xb);
        maxX = max(maxX, xb);
        minY = min(minY, min(yc0, yc1));
        maxY = max(maxY, max(yc0, yc1));
    }

    // Wave-wide min/max of the clamped footprint (identical across waves)
#pragma unroll
    for (int k = 1; k < 64; k <<= 1) {
        minX = min(minX, __shfl_xor(minX, k));
        maxX = max(maxX, __shfl_xor(maxX, k));
        minY = min(minY, __shfl_xor(minY, k));
        maxY = max(maxY, __shfl_xor(maxY, k));
    }
    // 16B-aligned 64-wide column window covering [xb, xb+1] for all lanes
    const int minX2 = min(minX, Wc - 64) & ~3;
    const bool valid = (maxY - minY + 1 <= PROWS) && (maxX - minX2 <= 62);

    const float* Rb = right + ((size_t)b * Cc + (size_t)(g * GCc + wid * CPW)) * HWc;
    const float* Lb = left  + ((size_t)b * Cc + (size_t)(g * GCc + wid * CPW)) * HWc + pix;

    float acc[Sc];
#pragma unroll
    for (int s = 0; s < Sc; ++s) acc[s] = 0.0f;

    if (valid) {
        // Per-sample: pair-row t holds rows (y09, y09+1); fold weights onto
        // the two fp16 slots by ROW IDENTITY (handles all clamp cases:
        // y0==-1 -> y09==y19 -> slot0 gets w00+w10; y0==79 -> w10=w11=0).
        unsigned wA[Sc], wB[Sc];
        int idx[Sc];
#pragma unroll
        for (int s = 0; s < Sc; ++s) {
            const int t  = y09[s] - minY;          // 0..PROWS-1 under valid
            const int sB = y19[s] - y09[s];        // 0 or 1
            const float A0 = w00[s] + (sB ? 0.0f : w10[s]);
            const float A1 = sB ? w10[s] : 0.0f;
            const float B0 = w01[s] + (sB ? 0.0f : w11[s]);
            const float B1 = sB ? w11[s] : 0.0f;
            wA[s] = pk(A0, A1);
            wB[s] = pk(B0, B1);
            // parity rotation: odd-t rows shifted +16 banks
            idx[s] = t * TSTRIDE + (xb9[s] - minX2) + (t & 1) * 16;
        }

        // Staging geometry: lane-group ls covers underlying rows
        // [5*ls, 5*ls+5] (6 rows, +1 overlap for vertical pairing),
        // 16B col segment seg. 21 underlying rows -> 20 pair-rows.
        const int ls  = lane >> 4;
        const int seg = lane & 15;
        int rowEl[6];
#pragma unroll
        for (int k = 0; k < 6; ++k)
            rowEl[k] = min(minY + 5 * ls + k, Hc - 1) * Wc + minX2 + seg * 4;

        // Write slots with matching parity rotation (loop-invariant).
        int wrow[5];
#pragma unroll
        for (int j = 0; j < 5; ++j) {
            const int tw5 = 5 * ls + j;
            wrow[j] = tw5 * TSTRIDE + seg * 4 + (tw5 & 1) * 16;
        }

        unsigned* twBase = &tile[wid][0][0];

        // Prologue: prefetch channels 0,1,2 into the three register sets.
        f4 rvA[6], rvB[6], rvC[6];
#pragma unroll
        for (int k = 0; k < 6; ++k) rvA[k] = *(const f4*)(Rb + rowEl[k]);
#pragma unroll
        for (int k = 0; k < 6; ++k) rvB[k] = *(const f4*)(Rb + HWc + rowEl[k]);
#pragma unroll
        for (int k = 0; k < 6; ++k) rvC[k] = *(const f4*)(Rb + 2 * HWc + rowEl[k]);
        float lvA = Lb[0];
        float lvB = Lb[HWc];
        float lvC = Lb[2 * (size_t)HWc];

        // Fully unrolled: regset = c % 3, buffer = c & 1 (LCM 6 | pattern).
        ITER3( 0, rvA, lvA, 0);
        ITER3( 1, rvB, lvB, 1);
        ITER3( 2, rvC, lvC, 0);
        ITER3( 3, rvA, lvA, 1);
        ITER3( 4, rvB, lvB, 0);
        ITER3( 5, rvC, lvC, 1);
        ITER3( 6, rvA, lvA, 0);
        ITER3( 7, rvB, lvB, 1);
        ITER3( 8, rvC, lvC, 0);
        ITER3( 9, rvA, lvA, 1);
        ITER3(10, rvB, lvB, 0);
        ITER3(11, rvC, lvC, 1);
        ITER3(12, rvA, lvA, 0);
        ITER3(13, rvB, lvB, 1);
        ITER3(14, rvC, lvC, 0);
        ITER3(15, rvA, lvA, 1);
    } else {
        // Fallback: direct global gathers, full f32 (footprint outliers)
        int offA[Sc], offB[Sc];
#pragma unroll
        for (int s = 0; s < Sc; ++s) {
            offA[s] = y09[s] * Wc + xb9[s];
            offB[s] = y19[s] * Wc + xb9[s];
        }
        for (int c = 0; c < CPW; ++c) {
            const float lv = Lb[(size_t)c * HWc];
            const float* Rc = Rb + (size_t)c * HWc;
#pragma unroll
            for (int s = 0; s < Sc; ++s) {
                const float vA0 = Rc[offA[s]];
                const float vA1 = Rc[offA[s] + 1];
                const float vB0 = Rc[offB[s]];
                const float vB1 = Rc[offB[s] + 1];
                acc[s] += lv * (w00[s] * vA0 + w01[s] * vA1 +
                                w10[s] * vB0 + w11[s] * vB1);
            }
        }
    }

    // 4-way cross-wave reduction; reduce buffer aliases the dead tile memory.
    float* red = (float*)&tile[0][0][0];   // 3*9*64*4 = 6912 B <= 51200 B
    __syncthreads();
    if (wid != 0) {
#pragma unroll
        for (int s = 0; s < Sc; ++s)
            red[((wid - 1) * Sc + s) * 64 + lane] = acc[s];
    }
    __syncthreads();
    if (wid == 0) {
        const float inv = 1.0f / (float)GCc;
        float* ob = out + ((size_t)b * Gc + g) * Sc * HWc + pix;
#pragma unroll
        for (int s = 0; s < Sc; ++s) {
            float v = acc[s];
#pragma unroll
            for (int ww = 1; ww < NW; ++ww)
                v += red[((ww - 1) * Sc + s) * 64 + lane];
            ob[(size_t)s * HWc] = v * inv;
        }
    }
}

extern "C" void kernel_launch(void* const* d_in, const int* in_sizes, int n_in,
                              void* d_out, int out_size, void* d_ws, size_t ws_size,
                              hipStream_t stream) {
    const float* left  = (const float*)d_in[0];
    const float* right = (const float*)d_in[1];
    const float* flow  = (const float*)d_in[2];
    const float* extra = (const float*)d_in[3];
    float* out = (float*)d_out;

    const int nblocks = Bc * Gc * H2c * WTc;  // 2*4*40*5 = 1600
    aoc_corr_kernel<<<nblocks, NW * 64, 0, stream>>>(left, right, flow, extra, out);
}

// Round 17
// 47.893 us; speedup vs baseline: 1.0024x; 1.0024x over previous
//
#include <hip/hip_runtime.h>

// Problem constants (fixed by the reference setup)
#define Bc   2
#define Cc   256
#define Hc   80
#define Wc   160
#define Gc   4
#define Sc   9
#define GCc  64              // channels per group
#define HWc  (Hc * Wc)
#define H2c  (Hc / 2)        // 40 row-pair tiles
#define WTc  (Wc / 32)       // 5 col tiles of 32
#define NW   4               // waves per block
#define CPW  16              // channels per wave

// fp16 vertical-pair tile: dword slot(t,x) = t*80 + dx; value =
// fp16x2(v(minY+t,x), v(minY+t+1,x)).
// R17: TRUE parity separation. R16's +(t&1)*16 rotation was a NO-OP:
// t*80 mod 32 = 16(t&1) already, so the added term made the bank mapping
// identical to stride 64 (conflict counter bit-identical 7,833,600 — proof).
// With the term removed, bank = (16(t&1) + dx) & 31: row-pair partner lanes
// (l, l+32; same dx, t differing by 1) land 16 banks apart instead of
// colliding every access; within a parity class dx ~ col + noise stays
// ~1 lane/bank. Write quad = (seg + 4((ls+j)&1)) & 7 -> 8 lanes/quad per
// b128 instr = conflict-free minimum.
// Proven config kept: __launch_bounds__(256,2) (>=3 spills rv sets to
// scratch — R13/R14), distance-3 prefetch, no hard lgkm fence (per-wave DS
// ops in-order; CFENCE pins compiler order vs TBAA — R6), XCD swizzle (R11).
#define PROWS   20
#define TSTRIDE 80
#define TDW     (PROWS * TSTRIDE)    // 1600 dwords = 6400 B per buffer

typedef float f4 __attribute__((ext_vector_type(4)));
typedef _Float16 h2 __attribute__((ext_vector_type(2)));
typedef unsigned u4 __attribute__((ext_vector_type(4)));

static __device__ __forceinline__ unsigned pk(float a, float b) {
    return __builtin_bit_cast(unsigned, __builtin_amdgcn_cvt_pkrtz(a, b));
}
static __device__ __forceinline__ float dot2(unsigned w, unsigned v, float c) {
#if __has_builtin(__builtin_amdgcn_fdot2)
    return __builtin_amdgcn_fdot2(__builtin_bit_cast(h2, w),
                                  __builtin_bit_cast(h2, v), c, false);
#else
    h2 hw = __builtin_bit_cast(h2, w), hv = __builtin_bit_cast(h2, v);
    return c + (float)hw[0] * (float)hv[0] + (float)hw[1] * (float)hv[1];
#endif
}

// Compiler-only memory fence (zero instructions).
#define CFENCE() asm volatile("" ::: "memory")

// One pipeline iteration, prefetch distance 3 (R12-proven). RV/LV statically
// named (rule #20); BUF compile-time 0/1. wrow[j] = precomputed write slot.
#define ITER3(cI, RV, LV, BUF)                                              \
  do {                                                                      \
    CFENCE();                                                               \
    _Pragma("unroll")                                                       \
    for (int j = 0; j < 5; ++j) {                                           \
      unsigned* q = twBase + (BUF) * TDW + wrow[j];                         \
      u4 val = { pk(RV[j][0], RV[j + 1][0]), pk(RV[j][1], RV[j + 1][1]),    \
                 pk(RV[j][2], RV[j + 1][2]), pk(RV[j][3], RV[j + 1][3]) };  \
      *(u4*)q = val;   /* ds_write_b128, conflict-free by construction */   \
    }                                                                       \
    CFENCE();                                                               \
    if ((cI) + 3 < CPW) {                                                   \
      const float* Rn = Rb + (size_t)((cI) + 3) * HWc;                      \
      _Pragma("unroll")                                                     \
      for (int k = 0; k < 6; ++k) RV[k] = *(const f4*)(Rn + rowEl[k]);      \
    }                                                                       \
    {                                                                       \
      const unsigned* twr = twBase + (BUF) * TDW;                           \
      _Pragma("unroll")                                                     \
      for (int s = 0; s < Sc; ++s) {                                        \
        const unsigned d0 = twr[idx[s]];                                    \
        const unsigned d1 = twr[idx[s] + 1];                                \
        float sd = dot2(wA[s], d0, 0.0f);                                   \
        sd = dot2(wB[s], d1, sd);                                           \
        acc[s] = fmaf(LV, sd, acc[s]);                                      \
      }                                                                     \
    }                                                                       \
    if ((cI) + 3 < CPW) LV = Lb[(size_t)((cI) + 3) * HWc];                  \
  } while (0)

__global__ __launch_bounds__(256, 2)
void aoc_corr_kernel(const float* __restrict__ left,
                     const float* __restrict__ right,
                     const float* __restrict__ flow,
                     const float* __restrict__ extra,
                     float* __restrict__ out)
{
    __shared__ unsigned tile[NW][2][TDW];   // 51200 B

    // XCD chunk swizzle (R11-proven: FETCH 122->30 MB): 1600 = 8 XCDs x 200,
    // and 200 = one (b,g)'s tiles; each XCD keeps one (b,g)'s 3.3 MB
    // right-slice resident in its 4 MB L2. Bijective. Perf heuristic only.
    const int p = blockIdx.x;
    int bid = 200 * (p & 7) + (p >> 3);

    int wt = bid % WTc; bid /= WTc;
    int h2i = bid % H2c; bid /= H2c;
    int g  = bid % Gc;  bid /= Gc;
    int b  = bid;

    const int tid  = threadIdx.x;
    const int wid  = tid >> 6;
    const int lane = tid & 63;
    const int r    = lane >> 5;
    const int col  = lane & 31;
    const int h    = h2i * 2 + r;
    const int w    = wt * 32 + col;
    const int pix  = h * Wc + w;

    const float* flowb = flow + (size_t)b * 2 * HWc;
    const float bx = (float)w + flowb[pix];
    const float by = (float)h + flowb[HWc + pix];

    int   xb9[Sc], y09[Sc], y19[Sc];
    float w00[Sc], w01[Sc], w10[Sc], w11[Sc];
    int minX = 1 << 30, maxX = -(1 << 30), minY = 1 << 30, maxY = -(1 << 30);

    const float* exb = extra + (size_t)b * (2 * Sc) * HWc + pix;
#pragma unroll
    for (int s = 0; s < Sc; ++s) {
        const float ex = exb[(size_t)(2 * s) * HWc];
        const float ey = exb[(size_t)(2 * s + 1) * HWc];
        const float x = bx + (float)(s - 4) + ex;   // window: x offset s-4, y 0
        const float y = by + ey;

        const float x0f = floorf(x);
        const float y0f = floorf(y);
        const float fx = x - x0f;
        const float fy = y - y0f;
        const int x0 = (int)x0f;
        const int y0 = (int)y0f;
        const int y1 = y0 + 1;

        const int xb = min(max(x0, 0), Wc - 2);
        const float cA = (x0 == xb) ? (1.0f - fx) : ((x0 == -1)     ? fx          : 0.0f);
        const float cB = (x0 == xb) ? fx          : ((x0 == Wc - 1) ? (1.0f - fx) : 0.0f);
        const float r0 = (y0 >= 0 && y0 < Hc) ? (1.0f - fy) : 0.0f;
        const float r1 = (y1 >= 0 && y1 < Hc) ? fy          : 0.0f;
        const int yc0 = min(max(y0, 0), Hc - 1);
        const int yc1 = min(max(y1, 0), Hc - 1);

        w00[s] = cA * r0;  w01[s] = cB * r0;
        w10[s] = cA * r1;  w11[s] = cB * r1;
        xb9[s] = xb;  y09[s] = yc0;  y19[s] = yc1;

        minX = min(minX, xb);
        maxX = max(maxX, xb);
        minY = min(minY, min(yc0, yc1));
        maxY = max(maxY, max(yc0, yc1));
    }

    // Wave-wide min/max of the clamped footprint (identical across waves)
#pragma unroll
    for (int k = 1; k < 64; k <<= 1) {
        minX = min(minX, __shfl_xor(minX, k));
        maxX = max(maxX, __shfl_xor(maxX, k));
        minY = min(minY, __shfl_xor(minY, k));
        maxY = max(maxY, __shfl_xor(maxY, k));
    }
    // 16B-aligned 64-wide column window covering [xb, xb+1] for all lanes
    const int minX2 = min(minX, Wc - 64) & ~3;
    const bool valid = (maxY - minY + 1 <= PROWS) && (maxX - minX2 <= 62);

    const float* Rb = right + ((size_t)b * Cc + (size_t)(g * GCc + wid * CPW)) * HWc;
    const float* Lb = left  + ((size_t)b * Cc + (size_t)(g * GCc + wid * CPW)) * HWc + pix;

    float acc[Sc];
#pragma unroll
    for (int s = 0; s < Sc; ++s) acc[s] = 0.0f;

    if (valid) {
        // Per-sample: pair-row t holds rows (y09, y09+1); fold weights onto
        // the two fp16 slots by ROW IDENTITY (handles all clamp cases:
        // y0==-1 -> y09==y19 -> slot0 gets w00+w10; y0==79 -> w10=w11=0).
        unsigned wA[Sc], wB[Sc];
        int idx[Sc];
#pragma unroll
        for (int s = 0; s < Sc; ++s) {
            const int t  = y09[s] - minY;          // 0..PROWS-1 under valid
            const int sB = y19[s] - y09[s];        // 0 or 1
            const float A0 = w00[s] + (sB ? 0.0f : w10[s]);
            const float A1 = sB ? w10[s] : 0.0f;
            const float B0 = w01[s] + (sB ? 0.0f : w11[s]);
            const float B1 = sB ? w11[s] : 0.0f;
            wA[s] = pk(A0, A1);
            wB[s] = pk(B0, B1);
            idx[s] = t * TSTRIDE + (xb9[s] - minX2);   // bank = 16(t&1)+dx
        }

        // Staging geometry: lane-group ls covers underlying rows
        // [5*ls, 5*ls+5] (6 rows, +1 overlap for vertical pairing),
        // 16B col segment seg. 21 underlying rows -> 20 pair-rows.
        const int ls  = lane >> 4;
        const int seg = lane & 15;
        int rowEl[6];
#pragma unroll
        for (int k = 0; k < 6; ++k)
            rowEl[k] = min(minY + 5 * ls + k, Hc - 1) * Wc + minX2 + seg * 4;

        // Write slots (loop-invariant; no rotation term — stride provides it).
        int wrow[5];
#pragma unroll
        for (int j = 0; j < 5; ++j)
            wrow[j] = (5 * ls + j) * TSTRIDE + seg * 4;

        unsigned* twBase = &tile[wid][0][0];

        // Prologue: prefetch channels 0,1,2 into the three register sets.
        f4 rvA[6], rvB[6], rvC[6];
#pragma unroll
        for (int k = 0; k < 6; ++k) rvA[k] = *(const f4*)(Rb + rowEl[k]);
#pragma unroll
        for (int k = 0; k < 6; ++k) rvB[k] = *(const f4*)(Rb + HWc + rowEl[k]);
#pragma unroll
        for (int k = 0; k < 6; ++k) rvC[k] = *(const f4*)(Rb + 2 * HWc + rowEl[k]);
        float lvA = Lb[0];
        float lvB = Lb[HWc];
        float lvC = Lb[2 * (size_t)HWc];

        // Fully unrolled: regset = c % 3, buffer = c & 1 (LCM 6 | pattern).
        ITER3( 0, rvA, lvA, 0);
        ITER3( 1, rvB, lvB, 1);
        ITER3( 2, rvC, lvC, 0);
        ITER3( 3, rvA, lvA, 1);
        ITER3( 4, rvB, lvB, 0);
        ITER3( 5, rvC, lvC, 1);
        ITER3( 6, rvA, lvA, 0);
        ITER3( 7, rvB, lvB, 1);
        ITER3( 8, rvC, lvC, 0);
        ITER3( 9, rvA, lvA, 1);
        ITER3(10, rvB, lvB, 0);
        ITER3(11, rvC, lvC, 1);
        ITER3(12, rvA, lvA, 0);
        ITER3(13, rvB, lvB, 1);
        ITER3(14, rvC, lvC, 0);
        ITER3(15, rvA, lvA, 1);
    } else {
        // Fallback: direct global gathers, full f32 (footprint outliers)
        int offA[Sc], offB[Sc];
#pragma unroll
        for (int s = 0; s < Sc; ++s) {
            offA[s] = y09[s] * Wc + xb9[s];
            offB[s] = y19[s] * Wc + xb9[s];
        }
        for (int c = 0; c < CPW; ++c) {
            const float lv = Lb[(size_t)c * HWc];
            const float* Rc = Rb + (size_t)c * HWc;
#pragma unroll
            for (int s = 0; s < Sc; ++s) {
                const float vA0 = Rc[offA[s]];
                const float vA1 = Rc[offA[s] + 1];
                const float vB0 = Rc[offB[s]];
                const float vB1 = Rc[offB[s] + 1];
                acc[s] += lv * (w00[s] * vA0 + w01[s] * vA1 +
                                w10[s] * vB0 + w11[s] * vB1);
            }
        }
    }

    // 4-way cross-wave reduction; reduce buffer aliases the dead tile memory.
    float* red = (float*)&tile[0][0][0];   // 3*9*64*4 = 6912 B <= 51200 B
    __syncthreads();
    if (wid != 0) {
#pragma unroll
        for (int s = 0; s < Sc; ++s)
            red[((wid - 1) * Sc + s) * 64 + lane] = acc[s];
    }
    __syncthreads();
    if (wid == 0) {
        const float inv = 1.0f / (float)GCc;
        float* ob = out + ((size_t)b * Gc + g) * Sc * HWc + pix;
#pragma unroll
        for (int s = 0; s < Sc; ++s) {
            float v = acc[s];
#pragma unroll
            for (int ww = 1; ww < NW; ++ww)
                v += red[((ww - 1) * Sc + s) * 64 + lane];
            ob[(size_t)s * HWc] = v * inv;
        }
    }
}

extern "C" void kernel_launch(void* const* d_in, const int* in_sizes, int n_in,
                              void* d_out, int out_size, void* d_ws, size_t ws_size,
                              hipStream_t stream) {
    const float* left  = (const float*)d_in[0];
    const float* right = (const float*)d_in[1];
    const float* flow  = (const float*)d_in[2];
    const float* extra = (const float*)d_in[3];
    float* out = (float*)d_out;

    const int nblocks = Bc * Gc * H2c * WTc;  // 2*4*40*5 = 1600
    aoc_corr_kernel<<<nblocks, NW * 64, 0, stream>>>(left, right, flow, extra, out);
}